// Round 16
// baseline (1060.167 us; speedup 1.0000x reference)
//
#include <hip/hip_runtime.h>
#include <hip/hip_bf16.h>
#include <stdint.h>

typedef uint16_t u16;
typedef uint32_t u32;
typedef float    f32x4  __attribute__((ext_vector_type(4)));
typedef __bf16   bf16x8 __attribute__((ext_vector_type(8)));
typedef u16      u16x8  __attribute__((ext_vector_type(8)));
typedef u16      u16x4  __attribute__((ext_vector_type(4)));
typedef u32      u32x2  __attribute__((ext_vector_type(2)));
typedef float    f32x4v __attribute__((ext_vector_type(4)));

// L=3120, D=1536, H=12, hd=128, FS=1560, NF=2, CACHE=6240, CTX=512, FF=8960
// current_start=3120 -> start_frame=2, window = [0,6240)

__device__ __forceinline__ u16 f2bf(float f) {
    u32 u = __builtin_bit_cast(u32, f);
    u32 r = u + 0x7fffu + ((u >> 16) & 1u);
    return (u16)(r >> 16);
}
__device__ __forceinline__ float bfbits2f(u32 ubits) {
    return __builtin_bit_cast(float, ubits << 16);
}
__device__ __forceinline__ u32 cvtpk(float a, float b) {
    u32 r;
    asm("v_cvt_pk_bf16_f32 %0, %1, %2" : "=v"(r) : "v"(a), "v"(b));
    return r;
}
__device__ __forceinline__ bf16x8 loadb8(const u16* p) {
    u16x8 u = *(const u16x8*)p;
    return __builtin_bit_cast(bf16x8, u);
}
__device__ __forceinline__ f32x4 mfma16(bf16x8 a, bf16x8 b, f32x4 c) {
    return __builtin_amdgcn_mfma_f32_16x16x32_bf16(a, b, c, 0, 0, 0);
}
__device__ __forceinline__ void gload16(const u16* gp, u16* lp) {
    __builtin_amdgcn_global_load_lds((const __attribute__((address_space(1))) void*)gp,
                                     (__attribute__((address_space(3))) void*)lp, 16, 0, 0);
}
// bijective XCD swizzle (m204): consecutive new-ids land on one XCD
__device__ __forceinline__ int xcdswz(int lin, int nwg) {
    int q = nwg >> 3, r = nwg & 7;
    int xcd = lin & 7, idx = lin >> 3;
    return (xcd < r) ? (xcd * (q + 1) + idx) : (r * (q + 1) + (xcd - r) * q + idx);
}
__device__ __forceinline__ float blockSum(float v, volatile float* buf, int t) {
#pragma unroll
    for (int o = 1; o < 64; o <<= 1) v += __shfl_xor(v, o);
    if ((t & 63) == 0) buf[t >> 6] = v;
    __syncthreads();
    float r = buf[0] + buf[1] + buf[2] + buf[3];
    __syncthreads();
    return r;
}

// ---------- weight conversion ----------
struct ConvJob { const float* s; u16* d; int n4; };
struct ConvJobs { ConvJob j[12]; int cnt; };

__global__ void k_conv(ConvJobs js) {
    int tid = blockIdx.x * blockDim.x + threadIdx.x;
    int stride = gridDim.x * blockDim.x;
    for (int q = 0; q < js.cnt; q++) {
        const f32x4v* s = (const f32x4v*)js.j[q].s;
        u16x4* d = (u16x4*)js.j[q].d;
        int n4 = js.j[q].n4;
        for (int i = tid; i < n4; i += stride) {
            f32x4v v = s[i];
            u16x4 o;
            o[0] = f2bf(v[0]); o[1] = f2bf(v[1]); o[2] = f2bf(v[2]); o[3] = f2bf(v[3]);
            d[i] = o;
        }
    }
}

__global__ void k_mod(const float* __restrict__ sst, const float* __restrict__ temb, float* __restrict__ e) {
    int i = blockIdx.x * 256 + threadIdx.x;
    if (i < 18432) e[i] = sst[i % 9216] + temb[i];
}

// KV cache rows [0,3120): K -> row-major (12,6240,128); V -> transposed (12,128,6240)
__global__ void k_cachecvt(const float* __restrict__ kc, const float* __restrict__ vc,
                           u16* __restrict__ Ka, u16* __restrict__ Va) {
    int b = blockIdx.x;                       // 6 * 195
    int hd = (b % 6) * 256 + threadIdx.x;
    int p0 = (b / 6) * 16;
    int h = hd >> 7, d = hd & 127;
    u16x8 lo, hi;
#pragma unroll
    for (int j = 0; j < 16; j++) {
        long src = (long)(p0 + j) * 1536 + hd;
        Ka[(long)h * 798720 + (long)(p0 + j) * 128 + d] = f2bf(kc[src]);
        u16 v = f2bf(vc[src]);
        if (j < 8) lo[j] = v; else hi[j - 8] = v;
    }
    u16* dst = &Va[(long)h * 798720 + (long)d * 6240 + p0];
    *(u16x8*)dst = lo;
    *(u16x8*)(dst + 8) = hi;
}

// ---------- LayerNorm (+ optional per-frame modulation) ----------
__global__ __launch_bounds__(256) void k_ln(const float* __restrict__ x, u16* __restrict__ out,
                                            const float* __restrict__ mulp, const float* __restrict__ addp,
                                            int perFrame, int plusOne) {
    __shared__ float buf[4];
    const int row = blockIdx.x, t = threadIdx.x;
    const float* xr = x + (long)row * 1536;
    float v[6];
    float s = 0.f;
#pragma unroll
    for (int k = 0; k < 6; k++) { v[k] = xr[t + k * 256]; s += v[k]; }
    s = blockSum(s, buf, t);
    float mu = s * (1.f / 1536.f);
    float q = 0.f;
#pragma unroll
    for (int k = 0; k < 6; k++) { float d = v[k] - mu; q += d * d; }
    q = blockSum(q, buf, t);
    float inv = rsqrtf(q * (1.f / 1536.f) + 1e-6f);
    const int fo = perFrame ? (row / 1560) * 9216 : 0;
    u16* orow = out + (long)row * 1536;
    float add1 = plusOne ? 1.f : 0.f;
#pragma unroll
    for (int k = 0; k < 6; k++) {
        int c = t + k * 256;
        float m = mulp[fo + c] + add1;
        float y = (v[k] - mu) * inv * m + addp[fo + c];
        orow[c] = f2bf(y);
    }
}

// ---------- RMS over D=1536 on bf16 input (+bias, + optional RoPE), head-split out ----------
__global__ __launch_bounds__(256) void k_rmsrope(const u16* __restrict__ in, int ld, int colOff,
                                                 const float* __restrict__ bias,
                                                 const float* __restrict__ w,
                                                 u16* __restrict__ out, long headStride,
                                                 const float* __restrict__ fr, const float* __restrict__ fi,
                                                 int doRope) {
    __shared__ float buf[4];
    const int row = blockIdx.x, t = threadIdx.x;
    const u32* xr = (const u32*)(in + (long)row * ld + colOff);
    const float2* b2 = (const float2*)bias;
    float px[3], py[3];
    float ss = 0.f;
#pragma unroll
    for (int i = 0; i < 3; i++) {
        u32 u = xr[t * 3 + i];
        float2 bb = b2[t * 3 + i];
        px[i] = bfbits2f(u & 0xffffu) + bb.x;
        py[i] = bfbits2f(u >> 16) + bb.y;
        ss += px[i] * px[i] + py[i] * py[i];
    }
    ss = blockSum(ss, buf, t);
    float inv = rsqrtf(ss * (1.f / 1536.f) + 1e-6f);
    int frame = 0, gh = 0, gw = 0;
    if (doRope) { frame = row / 1560; int rem = row - frame * 1560; gh = rem / 52; gw = rem - gh * 52; }
    const float2* w2 = (const float2*)w;
#pragma unroll
    for (int i = 0; i < 3; i++) {
        int jg = t * 3 + i;
        int hh = jg >> 6, j = jg & 63;
        float2 ww = w2[jg];
        float a = px[i] * inv * ww.x, b = py[i] * inv * ww.y;
        float oa = a, ob = b;
        if (doRope) {
            int fidx = (j < 22) ? (2 + frame) : ((j < 43) ? gh : gw);
            float cs = fr[fidx * 64 + j], sn = fi[fidx * 64 + j];
            oa = a * cs - b * sn;
            ob = a * sn + b * cs;
        }
        u16* dst = out + (long)hh * headStride + (long)row * 128 + j * 2;
        dst[0] = f2bf(oa);
        dst[1] = f2bf(ob);
    }
}

// ---------- fused dual RMS+RoPE for self-path Q (cols 0..1535) and K (cols 1536..3071) of lin ----------
__global__ __launch_bounds__(256) void k_rmsrope2(const u16* __restrict__ in,  // lin, ld 4608
                                                  const float* __restrict__ bq, const float* __restrict__ wq,
                                                  const float* __restrict__ bk, const float* __restrict__ wk,
                                                  u16* __restrict__ outQ, u16* __restrict__ outK,
                                                  const float* __restrict__ fr, const float* __restrict__ fi) {
    __shared__ float buf[8];
    const int row = blockIdx.x, t = threadIdx.x;
    const u32* xq = (const u32*)(in + (long)row * 4608);
    const u32* xk = xq + 768;
    const float2* bq2 = (const float2*)bq;
    const float2* bk2 = (const float2*)bk;
    float qx[3], qy[3], kx[3], ky[3];
    float sq = 0.f, sk = 0.f;
#pragma unroll
    for (int i = 0; i < 3; i++) {
        u32 uq = xq[t * 3 + i];
        float2 bb = bq2[t * 3 + i];
        qx[i] = bfbits2f(uq & 0xffffu) + bb.x;
        qy[i] = bfbits2f(uq >> 16) + bb.y;
        sq += qx[i] * qx[i] + qy[i] * qy[i];
        u32 uk = xk[t * 3 + i];
        float2 bc = bk2[t * 3 + i];
        kx[i] = bfbits2f(uk & 0xffffu) + bc.x;
        ky[i] = bfbits2f(uk >> 16) + bc.y;
        sk += kx[i] * kx[i] + ky[i] * ky[i];
    }
    sq = blockSum(sq, buf, t);
    sk = blockSum(sk, buf + 4, t);
    float invq = rsqrtf(sq * (1.f / 1536.f) + 1e-6f);
    float invk = rsqrtf(sk * (1.f / 1536.f) + 1e-6f);
    int frame = row / 1560;
    int rem = row - frame * 1560;
    int gh = rem / 52, gw = rem - gh * 52;
    const float2* wq2 = (const float2*)wq;
    const float2* wk2 = (const float2*)wk;
#pragma unroll
    for (int i = 0; i < 3; i++) {
        int jg = t * 3 + i;
        int hh = jg >> 6, j = jg & 63;
        int fidx = (j < 22) ? (2 + frame) : ((j < 43) ? gh : gw);
        float cs = fr[fidx * 64 + j], sn = fi[fidx * 64 + j];
        float2 wwq = wq2[jg];
        float a = qx[i] * invq * wwq.x, b = qy[i] * invq * wwq.y;
        u16* dq = outQ + (long)hh * (3120L * 128) + (long)row * 128 + j * 2;
        dq[0] = f2bf(a * cs - b * sn);
        dq[1] = f2bf(a * sn + b * cs);
        float2 wwk = wk2[jg];
        float c2 = kx[i] * invk * wwk.x, d2 = ky[i] * invk * wwk.y;
        u16* dk = outK + (long)hh * (6240L * 128) + (long)row * 128 + j * 2;
        dk[0] = f2bf(c2 * cs - d2 * sn);
        dk[1] = f2bf(c2 * sn + d2 * cs);
    }
}

// ---------- scatter bf16 cols (+bias) into V-transposed head-split layout (16-wide) ----------
__global__ void k_scatterT(const u16* __restrict__ in, int ld, int colOff,
                           const float* __restrict__ bias, u16* __restrict__ outT,
                           int vstride, int posOff) {
    int hd = blockIdx.x * 256 + threadIdx.x;   // 0..1535
    int r0 = blockIdx.y * 16;
    int h = hd >> 7, d = hd & 127;
    float bi = bias[hd];
    u16x8 lo, hi;
#pragma unroll
    for (int j = 0; j < 16; j++) {
        u16 v = f2bf(bfbits2f(in[(long)(r0 + j) * ld + colOff + hd]) + bi);
        if (j < 8) lo[j] = v; else hi[j - 8] = v;
    }
    u16* dst = &outT[(long)h * 128 * vstride + (long)d * vstride + posOff + r0];
    *(u16x8*)dst = lo;
    *(u16x8*)(dst + 8) = hi;
}

// ---------- GEMM: C(MxN) = A(MxK) @ B(NxK)^T (+bias), tile BM x 128 (direct mapping) ----------
// EPI 0: f32  1: bf16  2: bf16 gelu  3: f32 resid + v*gate  5: f32 split-K partial
struct GemmP {
    const u16* A; const u16* B; void* C;
    const float* bias; const float* gate; const float* resid;
    int M, N, K, ldA, ldB, ldC, kChunk;
};

template <int EPI, int BM>
__global__ __launch_bounds__(256) void k_gemm(GemmP g) {
    constexpr int WM = BM / 2;    // rows per m-wave
    constexpr int TM = BM / 32;   // m-frags per wave
    __shared__ alignas(16) u16 As[BM * 32];
    __shared__ alignas(16) u16 Bs[128 * 32];
    const int t = threadIdx.x;
    const int w = t >> 6, l = t & 63, lr = l & 15, lg = l >> 4;
    const int wm = w >> 1, wn = w & 1;
    const long m0 = (long)blockIdx.y * BM, n0 = (long)blockIdx.x * 128;
    f32x4 acc[TM][4];
#pragma unroll
    for (int a = 0; a < TM; a++)
#pragma unroll
        for (int b = 0; b < 4; b++) acc[a][b] = f32x4{0.f, 0.f, 0.f, 0.f};

    const int rowU = t >> 2, c8 = t & 3;
    long arow[2], brow[2];
#pragma unroll
    for (int i = 0; i < 2; i++) {
        long r = m0 + rowU + i * 64;
        if (r > (long)g.M - 1) r = g.M - 1;
        arow[i] = r;
        brow[i] = n0 + rowU + i * 64;
    }

    const int kBeg = blockIdx.z * g.kChunk;
    const int kEnd = min(g.K, kBeg + g.kChunk);
    for (int k0 = kBeg; k0 < kEnd; k0 += 32) {
        __syncthreads();
#pragma unroll
        for (int i = 0; i < BM / 64; i++)
            gload16(g.A + arow[i] * (long)g.ldA + k0 + c8 * 8, &As[(i * 256 + w * 64) * 8]);
#pragma unroll
        for (int i = 0; i < 2; i++)
            gload16(g.B + brow[i] * (long)g.ldB + k0 + c8 * 8, &Bs[(i * 256 + w * 64) * 8]);
        __syncthreads();
        bf16x8 am[TM], bn[4];
#pragma unroll
        for (int mi = 0; mi < TM; mi++) am[mi] = loadb8(&As[(wm * WM + mi * 16 + lr) * 32 + lg * 8]);
#pragma unroll
        for (int ni = 0; ni < 4; ni++) bn[ni] = loadb8(&Bs[(wn * 64 + ni * 16 + lr) * 32 + lg * 8]);
#pragma unroll
        for (int mi = 0; mi < TM; mi++)
#pragma unroll
            for (int ni = 0; ni < 4; ni++)
                acc[mi][ni] = mfma16(am[mi], bn[ni], acc[mi][ni]);
    }

#pragma unroll
    for (int mi = 0; mi < TM; mi++) {
#pragma unroll
        for (int ni = 0; ni < 4; ni++) {
            long col = n0 + wn * 64 + ni * 16 + lr;
            float bi = g.bias ? g.bias[col] : 0.f;
#pragma unroll
            for (int r = 0; r < 4; r++) {
                long row = m0 + wm * WM + mi * 16 + lg * 4 + r;
                if (row >= g.M) continue;
                float v = acc[mi][ni][r] + bi;
                if constexpr (EPI == 0) {
                    ((float*)g.C)[row * g.ldC + col] = v;
                } else if constexpr (EPI == 1) {
                    ((u16*)g.C)[row * g.ldC + col] = f2bf(v);
                } else if constexpr (EPI == 2) {
                    float x3 = v * v * v;
                    float gl = 0.5f * v * (1.f + tanhf(0.79788456080286536f * (v + 0.044715f * x3)));
                    ((u16*)g.C)[row * g.ldC + col] = f2bf(gl);
                } else if constexpr (EPI == 3) {
                    float gt = g.gate ? g.gate[(row / 1560) * 9216 + col] : 1.f;
                    ((float*)g.C)[row * g.ldC + col] = g.resid[row * g.ldC + col] + v * gt;
                } else { // 5: split-K partial
                    ((float*)g.C)[(long)blockIdx.z * ((long)g.M * g.ldC) + row * g.ldC + col] = v;
                }
            }
        }
    }
}

// ---------- 256x256 multi-phase GEMM (BK=64, dbuf LDS, XOR-swizzle, XCD-swizzled) ----------
// EPI 1: bf16  2: bf16 gelu.
template <int EPI>
__global__ __launch_bounds__(512, 2) void k_gemm256(GemmP g) {
    __shared__ alignas(16) u16 As[2][16384];
    __shared__ alignas(16) u16 Bs[2][16384];
    const int t = threadIdx.x;
    const int wid = t >> 6, l = t & 63, lr = l & 15, lg = l >> 4;
    const int wm = wid >> 2, wn = wid & 3;

    const int nx = gridDim.x;
    int lin = xcdswz(blockIdx.y * nx + blockIdx.x, nx * gridDim.y);
    const long m0 = (long)(lin / nx) * 256, n0 = (long)(lin % nx) * 256;
    const int nt = g.K >> 6;

    f32x4 acc[8][4];
#pragma unroll
    for (int a = 0; a < 8; a++)
#pragma unroll
        for (int b = 0; b < 4; b++) acc[a][b] = f32x4{0.f, 0.f, 0.f, 0.f};

    const int su = t >> 3;          // row-within-issue 0..63
    const int sc = t & 7;           // 16B chunk 0..7
    const int ldsBase = (wid << 9); // wave-uniform, u16 units

    auto stA = [&](int b, int tk, int j) {
        int r = j * 64 + su;
        long row = m0 + r; if (row > (long)g.M - 1) row = g.M - 1;
        gload16(g.A + row * (long)g.ldA + tk * 64 + ((sc ^ (r & 7)) * 8),
                &As[b][(j << 12) + ldsBase]);
    };
    auto stB = [&](int b, int tk, int j) {
        int r = j * 64 + su;
        long row = n0 + r; if (row > (long)g.N - 1) row = g.N - 1;
        gload16(g.B + row * (long)g.ldB + tk * 64 + ((sc ^ (r & 7)) * 8),
                &Bs[b][(j << 12) + ldsBase]);
    };

    // prologue: full tile 0 into buffer 0
#pragma unroll
    for (int j = 0; j < 4; j++) stA(0, 0, j);
#pragma unroll
    for (int j = 0; j < 4; j++) stB(0, 0, j);
    __syncthreads();

    for (int tk = 0; tk < nt; ++tk) {
        const int cur = tk & 1, nxt = cur ^ 1;
        const bool pre = (tk + 1 < nt);
        bf16x8 bB[4][2];
#pragma unroll
        for (int ph = 0; ph < 4; ++ph) {
            if (pre) {
                if (ph == 0) { stA(nxt, tk + 1, 0); stA(nxt, tk + 1, 1); stA(nxt, tk + 1, 2); stA(nxt, tk + 1, 3); }
                else if (ph == 1) { stB(nxt, tk + 1, 0); stB(nxt, tk + 1, 1); stB(nxt, tk + 1, 2); stB(nxt, tk + 1, 3); }
            }
            if (ph == 0) {
#pragma unroll
                for (int ni = 0; ni < 4; ni++)
#pragma unroll
                    for (int kk = 0; kk < 2; kk++) {
                        int row = wn * 64 + ni * 16 + lr;
                        bB[ni][kk] = loadb8(&Bs[cur][row * 64 + (((kk * 4 + lg) ^ (lr & 7)) * 8)]);
                    }
            }
            bf16x8 aA[2][2];
#pragma unroll
            for (int mi2 = 0; mi2 < 2; mi2++)
#pragma unroll
                for (int kk = 0; kk < 2; kk++) {
                    int row = wm * 128 + (ph * 2 + mi2) * 16 + lr;
                    aA[mi2][kk] = loadb8(&As[cur][row * 64 + (((kk * 4 + lg) ^ (lr & 7)) * 8)]);
                }
            __builtin_amdgcn_s_setprio(1);
#pragma unroll
            for (int mi2 = 0; mi2 < 2; mi2++)
#pragma unroll
                for (int ni = 0; ni < 4; ni++)
#pragma unroll
                    for (int kk = 0; kk < 2; kk++)
                        acc[ph * 2 + mi2][ni] = mfma16(aA[mi2][kk], bB[ni][kk], acc[ph * 2 + mi2][ni]);
            __builtin_amdgcn_s_setprio(0);
            __builtin_amdgcn_sched_barrier(0);
        }
        __syncthreads();
    }

#pragma unroll
    for (int mi = 0; mi < 8; mi++) {
#pragma unroll
        for (int ni = 0; ni < 4; ni++) {
            long col = n0 + wn * 64 + ni * 16 + lr;
            float bi = g.bias ? g.bias[col] : 0.f;
#pragma unroll
            for (int r = 0; r < 4; r++) {
                long row = m0 + wm * 128 + mi * 16 + lg * 4 + r;
                if (row >= g.M) continue;
                float v = acc[mi][ni][r] + bi;
                if constexpr (EPI == 1) {
                    ((u16*)g.C)[row * g.ldC + col] = f2bf(v);
                } else { // 2: gelu(tanh)
                    float x3 = v * v * v;
                    float gl = 0.5f * v * (1.f + tanhf(0.79788456080286536f * (v + 0.044715f * x3)));
                    ((u16*)g.C)[row * g.ldC + col] = f2bf(gl);
                }
            }
        }
    }
}

// ---------- split-K combine for FFN2: out = resid + (sum partials + bias)*gate ----------
__global__ void k_gcomb(const float* __restrict__ P, int S, long MN4,
                        const float* __restrict__ bias, const float* __restrict__ gate,
                        const float* __restrict__ resid, float* __restrict__ out) {
    long i = (long)blockIdx.x * 256 + threadIdx.x;
    if (i >= MN4) return;
    f32x4v a = ((const f32x4v*)P)[i];
    for (int s = 1; s < S; s++) {
        f32x4v b = ((const f32x4v*)P)[(long)s * MN4 + i];
        a[0] += b[0]; a[1] += b[1]; a[2] += b[2]; a[3] += b[3];
    }
    long e0 = i * 4;
    int col = (int)(e0 % 1536);
    int fo = (int)((e0 / 1536) / 1560) * 9216;
    f32x4v r = ((const f32x4v*)resid)[i];
#pragma unroll
    for (int j = 0; j < 4; j++)
        r[j] += (a[j] + bias[col + j]) * gate[fo + col + j];
    ((f32x4v*)out)[i] = r;
}

// ---------- split-K partial sum -> bf16 ----------
__global__ void k_sumbf(const float* __restrict__ P, int S, long N4, u16* __restrict__ out) {
    long i = (long)blockIdx.x * 256 + threadIdx.x;
    if (i >= N4) return;
    f32x4v a = ((const f32x4v*)P)[i];
#pragma unroll 3
    for (int s = 1; s < S; s++) {
        f32x4v b = ((const f32x4v*)P)[(long)s * N4 + i];
        a[0] += b[0]; a[1] += b[1]; a[2] += b[2]; a[3] += b[3];
    }
    u16x4 o;
    o[0] = f2bf(a[0]); o[1] = f2bf(a[1]); o[2] = f2bf(a[2]); o[3] = f2bf(a[3]);
    ((u16x4*)out)[i] = o;
}

// ---------- flash attention: swapped QK^T, in-register softmax, O^T accumulation ----------
// XCD-swizzled block mapping: blocks sharing one head's K/V panel land on one XCD's L2.
__global__ __launch_bounds__(256) void k_flash(const u16* __restrict__ Qb, const u16* __restrict__ Kb,
                                               const u16* __restrict__ Vtg,
                                               u16* __restrict__ Opart, float2* __restrict__ ms,
                                               int kvLen, int qlen, int splitIters, int totIters) {
    __shared__ alignas(16) u16 Kt[32 * 136];   // [key][128+8]
    __shared__ alignas(16) u16 Vt[128 * 40];   // [d][32+8]
    __shared__ alignas(16) u16 Pt[4][32 * 40]; // per wave [q][32+8]
    const int t = threadIdx.x;
    const int w = t >> 6, l = t & 63, lr = l & 15, lg = l >> 4;

    const int nqb = gridDim.x, nh = gridDim.y;
    int lin = xcdswz(blockIdx.x + nqb * (blockIdx.y + nh * blockIdx.z), nqb * nh * gridDim.z);
    const int qb = lin % nqb;
    const int head = (lin / nqb) % nh;
    const int z = lin / (nqb * nh);

    const long q0 = (long)qb * 128;
    const u16* Qh = Qb + (long)head * qlen * 128;
    const u16* Kh = Kb + (long)head * kvLen * 128;
    const u16* Vh = Vtg + (long)head * kvLen * 128; // [128][kvLen]
    constexpr float SCL2 = 0.08838834764831845f * 1.44269504088896f; // 1/sqrt(128) * log2(e)

    bf16x8 aq[2][4];
#pragma unroll
    for (int wq = 0; wq < 2; wq++)
#pragma unroll
        for (int c = 0; c < 4; c++) {
            long row = q0 + w * 32 + wq * 16 + lr;
            if (row > (long)qlen - 1) row = qlen - 1;
            aq[wq][c] = loadb8(Qh + row * 128 + c * 32 + lg * 8);
        }

    f32x4 o[2][8];
    float mrow[2] = {-1e30f, -1e30f}, srow[2] = {0.f, 0.f};  // srow per-lane partial until end
#pragma unroll
    for (int wq = 0; wq < 2; wq++)
#pragma unroll
        for (int db = 0; db < 8; db++) o[wq][db] = f32x4{0.f, 0.f, 0.f, 0.f};

    const int kr = t >> 4, c16 = (t & 15) * 8;
    const int vr = t >> 1, vh = (t & 1) * 16;

    const int it0 = z * splitIters;
    const int itN = min(totIters, it0 + splitIters);
    for (int kt = it0; kt < itN; kt++) {
        const long k0 = (long)kt * 32;
        __syncthreads();
        {
            u16x8 a0 = *(const u16x8*)(Kh + (k0 + kr) * 128 + c16);
            u16x8 a1 = *(const u16x8*)(Kh + (k0 + kr + 16) * 128 + c16);
            *(u16x8*)&Kt[kr * 136 + c16] = a0;
            *(u16x8*)&Kt[(kr + 16) * 136 + c16] = a1;
            u16x8 b0 = *(const u16x8*)(Vh + (long)vr * kvLen + k0 + vh);
            u16x8 b1 = *(const u16x8*)(Vh + (long)vr * kvLen + k0 + vh + 8);
            *(u16x8*)&Vt[vr * 40 + vh] = b0;
            *(u16x8*)&Vt[vr * 40 + vh + 8] = b1;
        }
        __syncthreads();

        f32x4 s[2][2];
#pragma unroll
        for (int kh = 0; kh < 2; kh++) {
            bf16x8 kf[4];
#pragma unroll
            for (int cb = 0; cb < 4; cb++)
                kf[cb] = loadb8(&Kt[(kh * 16 + lr) * 136 + cb * 32 + lg * 8]);
#pragma unroll
            for (int wq = 0; wq < 2; wq++) {
                f32x4 acc = f32x4{0.f, 0.f, 0.f, 0.f};
#pragma unroll
                for (int cb = 0; cb < 4; cb++) acc = mfma16(kf[cb], aq[wq][cb], acc);
                s[wq][kh] = acc;
            }
        }

#pragma unroll
        for (int wq = 0; wq < 2; wq++) {
            float pml = fmaxf(fmaxf(fmaxf(s[wq][0][0], s[wq][0][1]), fmaxf(s[wq][0][2], s[wq][0][3])),
                              fmaxf(fmaxf(s[wq][1][0], s[wq][1][1]), fmaxf(s[wq][1][2], s[wq][1][3])));
            if (__any(pml * SCL2 > mrow[wq] + 8.f)) {
                float pm = fmaxf(pml, __shfl_xor(pml, 16));
                pm = fmaxf(pm, __shfl_xor(pm, 32));
                float nm = fmaxf(mrow[wq], pm * SCL2);
                float fsc = exp2f(mrow[wq] - nm);
                mrow[wq] = nm;
                srow[wq] *= fsc;
#pragma unroll
                for (int db = 0; db < 8; db++) {
                    f32x4 t4 = o[wq][db];
                    t4[0] *= fsc; t4[1] *= fsc; t4[2] *= fsc; t4[3] *= fsc;
                    o[wq][db] = t4;
                }
            }
            float p[8];
#pragma unroll
            for (int kh = 0; kh < 2; kh++)
#pragma unroll
                for (int r = 0; r < 4; r++)
                    p[kh * 4 + r] = exp2f(fmaf(s[wq][kh][r], SCL2, -mrow[wq]));
            srow[wq] += ((p[0] + p[1]) + (p[2] + p[3])) + ((p[4] + p[5]) + (p[6] + p[7]));
            u32x2 wa, wb;
            wa[0] = cvtpk(p[0], p[1]); wa[1] = cvtpk(p[2], p[3]);
            wb[0] = cvtpk(p[4], p[5]); wb[1] = cvtpk(p[6], p[7]);
            u16* pp = &Pt[w][(wq * 16 + lr) * 40 + lg * 4];
            *(u32x2*)pp = wa;
            *(u32x2*)(pp + 16) = wb;
        }

        bf16x8 pb0 = loadb8(&Pt[w][lr * 40 + lg * 8]);
        bf16x8 pb1 = loadb8(&Pt[w][(16 + lr) * 40 + lg * 8]);
#pragma unroll
        for (int db = 0; db < 8; db++) {
            bf16x8 vf = loadb8(&Vt[(db * 16 + lr) * 40 + lg * 8]);
            o[0][db] = mfma16(vf, pb0, o[0][db]);
            o[1][db] = mfma16(vf, pb1, o[1][db]);
        }
    }

#pragma unroll
    for (int wq = 0; wq < 2; wq++) {
        srow[wq] += __shfl_xor(srow[wq], 16);
        srow[wq] += __shfl_xor(srow[wq], 32);
    }

    const long part = ((long)z * 12 + head) * qlen;
#pragma unroll
    for (int wq = 0; wq < 2; wq++) {
        long row = q0 + w * 32 + wq * 16 + lr;
        if (row < qlen) {
            if (lg == 0) {
                float2 v; v.x = mrow[wq]; v.y = srow[wq];
                ms[part + row] = v;
            }
#pragma unroll
            for (int db = 0; db < 8; db++) {
                u16x4 pk;
#pragma unroll
                for (int r = 0; r < 4; r++) pk[r] = f2bf(o[wq][db][r]);
                *(u16x4*)&Opart[(part + row) * 128 + db * 16 + lg * 4] = pk;
            }
        }
    }
}

// ---------- combine KV-split partials (m,l in log2 units) ----------
__global__ __launch_bounds__(256) void k_combine(const u16* __restrict__ Opart, const float2* __restrict__ ms,
                                                 u16* __restrict__ Ob, int qlen, int S) {
    int idx = blockIdx.x * 4 + (threadIdx.x >> 6);
    int l = threadIdx.x & 63;
    int h = idx / qlen, q = idx - h * qlen;
    float2 mm[6];
    float M = -1e30f;
    for (int s = 0; s < S; s++) {
        mm[s] = ms[((long)s * 12 + h) * qlen + q];
        M = fmaxf(M, mm[s].x);
    }
    float den = 0.f, a0 = 0.f, a1 = 0.f;
    for (int s = 0; s < S; s++) {
        float wgt = exp2f(mm[s].x - M);
        den += wgt * mm[s].y;
        u32 two = *(const u32*)&Opart[(((long)s * 12 + h) * qlen + q) * 128 + l * 2];
        a0 += wgt * bfbits2f(two & 0xffffu);
        a1 += wgt * bfbits2f(two >> 16);
    }
    float inv = 1.f / den;
    u32 o = ((u32)f2bf(a1 * inv) << 16) | (u32)f2bf(a0 * inv);
    *(u32*)&Ob[(long)q * 1536 + h * 128 + l * 2] = o;
}

// ---------- launch ----------
extern "C" void kernel_launch(void* const* d_in, const int* in_sizes, int n_in,
                              void* d_out, int out_size, void* d_ws, size_t ws_size,
                              hipStream_t stream) {
    const float* hs    = (const float*)d_in[0];
    const float* ctx   = (const float*)d_in[1];
    const float* temb  = (const float*)d_in[2];
    const float* fr    = (const float*)d_in[3];
    const float* fi    = (const float*)d_in[4];
    const float* kcache= (const float*)d_in[5];
    const float* vcache= (const float*)d_in[6];
    const float* sst   = (const float*)d_in[7];
    const float* Wq = (const float*)d_in[8],  *bq = (const float*)d_in[9];
    const float* Wk = (const float*)d_in[10], *bk = (const float*)d_in[11];
    const float* Wv = (const float*)d_in[12], *bv = (const float*)d_in[13];
    const float* Wo = (const float*)d_in[14], *bo = (const float*)d_in[15];
    const float* nqw = (const float*)d_in[16], *nkw = (const float*)d_in[17];
    const float* salnw = (const float*)d_in[18], *salnb = (const float*)d_in[19];
    const float* cWq = (const float*)d_in[20], *cbq = (const float*)d_in[21];
    const float* cWk = (const float*)d_in[22], *cbk = (const float*)d_in[23];
    const float* cWv = (const float*)d_in[24], *cbv = (const float*)d_in[25];
    const float* cWo = (const float*)d_in[26], *cbo = (const float*)d_in[27];
    const float* cnqw = (const float*)d_in[28], *cnkw = (const float*)d_in[29];
    const float* W1 = (const float*)d_in[30], *b1 = (const float*)d_in[31];
    const float* W2 = (const float*)d_in[32], *b2 = (const float*)d_in[33];
    float* out = (float*)d_out;

    char* base = (char*)d_ws;
    size_t off = 0;
    auto alloc = [&](size_t bytes) -> char* {
        char* p = base + off;
        off = (off + bytes + 255) & ~(size_t)255;
        return p;
    };
    float* e   = (float*)alloc(18432 * 4);
    u16* nbuf  = (u16*)alloc((size_t)3120 * 1536 * 2);
    u16* lin   = (u16*)alloc((size_t)3120 * 4608 * 2);   // qkv proj; also ms; also FFN2 partials (w/ Qb)
    u16* Qb    = (u16*)alloc((size_t)12 * 3120 * 128 * 2);
    u16* Ka    = (u16*)alloc((size_t)12 * 6240 * 128 * 2);
    u16* Va    = (u16*)alloc((size_t)12 * 6240 * 128 * 2); // TRANSPOSED (12,128,6240)
    u16* attnb = (u16*)alloc((size_t)3120 * 1536 * 2);
    float* X1  = (float*)alloc((size_t)3120 * 1536 * 4);
    u16* CKb   = (u16*)alloc((size_t)12 * 512 * 128 * 2);
    u16* CVt   = (u16*)alloc((size_t)12 * 512 * 128 * 2);  // TRANSPOSED (12,128,512)
    u16* H1    = (u16*)alloc((size_t)3120 * 8960 * 2);   // FFN hidden; also Opart; also cKV partials
    u16* wqkv_b= (u16*)alloc((size_t)4608 * 1536 * 2);
    u16* wo_b  = (u16*)alloc((size_t)1536 * 1536 * 2);
    u16* cwq_b = (u16*)alloc((size_t)1536 * 1536 * 2);
    u16* cwkv_b= (u16*)alloc((size_t)3072 * 1536 * 2);
    u16* cwo_b = (u16*)alloc((size_t)1536 * 1536 * 2);
    u16* w1_b  = (u16*)alloc((size_t)8960 * 1536 * 2);
    u16* w2_b  = (u16*)alloc((size_t)8960 * 1536 * 2);
    u16* ctxb  = (u16*)alloc((size_t)512 * 1536 * 2);

    u16* Opart = H1;              // 5*12*3120*128 bf16 = 47.9MB < 55.9MB
    float2* msb = (float2*)lin;   // 5*12*3120 float2
    float* pbuf = (float*)lin;    // FFN2 partials: 2*3120*1536*4 = 38.3MB = lin+Qb, both dead
    float* cpart = (float*)H1;    // cKV partials: 4*512*3072*4 = 25.2MB

    // 1. convert weights + ctx to bf16
    ConvJobs cj{};
    auto setj = [&](int i, const float* s, u16* d, int n) { cj.j[i].s = s; cj.j[i].d = d; cj.j[i].n4 = n / 4; };
    setj(0, Wq, wqkv_b, 1536 * 1536);
    setj(1, Wk, wqkv_b + (size_t)1536 * 1536, 1536 * 1536);
    setj(2, Wv, wqkv_b + (size_t)2 * 1536 * 1536, 1536 * 1536);
    setj(3, Wo, wo_b, 1536 * 1536);
    setj(4, cWq, cwq_b, 1536 * 1536);
    setj(5, cWk, cwkv_b, 1536 * 1536);
    setj(6, cWv, cwkv_b + (size_t)1536 * 1536, 1536 * 1536);
    setj(7, cWo, cwo_b, 1536 * 1536);
    setj(8, W1, w1_b, 8960 * 1536);
    setj(9, W2, w2_b, 8960 * 1536);
    setj(10, ctx, ctxb, 512 * 1536);
    cj.cnt = 11;
    k_conv<<<2048, 256, 0, stream>>>(cj);

    // 2. modulation + cache repack (K row-major, V transposed)
    k_mod<<<72, 256, 0, stream>>>(sst, temb, e);
    k_cachecvt<<<1170, 256, 0, stream>>>(kcache, vcache, Ka, Va);

    // 3. nh = LN(x)*(1+scale)+shift
    k_ln<<<3120, 256, 0, stream>>>(hs, nbuf, e + 1536, e + 0, 1, 1);

    // 4. fused QKV projection (256² multi-phase) -> lin, then fused dual RMS/RoPE + scatterT
    GemmP gqkv{nbuf, wqkv_b, lin, nullptr, nullptr, nullptr, 3120, 4608, 1536, 1536, 1536, 4608, 1536};
    k_gemm256<1><<<dim3(18, 13), 512, 0, stream>>>(gqkv);
    k_rmsrope2<<<3120, 256, 0, stream>>>(lin, bq, nqw, bk, nkw, Qb, Ka + (size_t)3120 * 128, fr, fi);
    k_scatterT<<<dim3(6, 195), 256, 0, stream>>>(lin, 4608, 3072, bv, Va, 6240, 3120);

    // 5. self-attention: 195 tiles of 32 keys, split 5 (39 each), XCD-swizzled
    k_flash<<<dim3(25, 12, 5), 256, 0, stream>>>(Qb, Ka, Va, Opart, msb, 6240, 3120, 39, 195);
    k_combine<<<9360, 256, 0, stream>>>(Opart, msb, attnb, 3120, 5);

    // 6. x1 = x + (attn@Wo^T + bo)*gate
    GemmP gwo{attnb, wo_b, X1, bo, e + 2 * 1536, hs, 3120, 1536, 1536, 1536, 1536, 1536, 1536};
    k_gemm<3, 64><<<dim3(12, 49), 256, 0, stream>>>(gwo);

    // 7. n2 = LN(x1)*saln_w + saln_b
    k_ln<<<3120, 256, 0, stream>>>(X1, nbuf, salnw, salnb, 0, 0);

    // 8. cross-attn projections
    GemmP gcq{nbuf, cwq_b, lin, nullptr, nullptr, nullptr, 3120, 1536, 1536, 1536, 1536, 1536, 1536};
    k_gemm<1, 64><<<dim3(12, 49), 256, 0, stream>>>(gcq);
    k_rmsrope<<<3120, 256, 0, stream>>>(lin, 1536, 0, cbq, cnqw, Qb, (long)3120 * 128, fr, fi, 0);

    GemmP gckv{ctxb, cwkv_b, cpart, nullptr, nullptr, nullptr, 512, 3072, 1536, 1536, 1536, 3072, 384};
    k_gemm<5, 64><<<dim3(24, 8, 4), 256, 0, stream>>>(gckv);
    k_sumbf<<<1536, 256, 0, stream>>>(cpart, 4, 393216, lin);
    k_rmsrope<<<512, 256, 0, stream>>>(lin, 3072, 0, cbk, cnkw, CKb, (long)512 * 128, fr, fi, 0);
    k_scatterT<<<dim3(6, 32), 256, 0, stream>>>(lin, 3072, 1536, cbv, CVt, 512, 0);

    // 9. cross-attention: 16 tiles of 32 keys, split 2 (8 each)
    k_flash<<<dim3(25, 12, 2), 256, 0, stream>>>(Qb, CKb, CVt, Opart, msb, 512, 3120, 8, 16);
    k_combine<<<9360, 256, 0, stream>>>(Opart, msb, attnb, 3120, 2);

    // 10. x2 = x1 + ca@cWo^T + cbo   (in-place on X1)
    GemmP gcwo{attnb, cwo_b, X1, cbo, nullptr, X1, 3120, 1536, 1536, 1536, 1536, 1536, 1536};
    k_gemm<3, 64><<<dim3(12, 49), 256, 0, stream>>>(gcwo);

    // 11. n3 = LN(x2)*(1+c_scale)+c_shift
    k_ln<<<3120, 256, 0, stream>>>(X1, nbuf, e + 4 * 1536, e + 3 * 1536, 1, 1);

    // 12. FFN: FFN1 256² multi-phase; FFN2 BM=64 split-K x2 + combine
    GemmP g1{nbuf, w1_b, H1, b1, nullptr, nullptr, 3120, 8960, 1536, 1536, 1536, 8960, 1536};
    k_gemm256<2><<<dim3(35, 13), 512, 0, stream>>>(g1);

    GemmP g2{H1, w2_b, pbuf, nullptr, nullptr, nullptr, 3120, 1536, 8960, 8960, 8960, 1536, 4480};
    k_gemm<5, 64><<<dim3(12, 49, 2), 256, 0, stream>>>(g2);
    k_gcomb<<<4680, 256, 0, stream>>>(pbuf, 2, 1198080, b2, e + 5 * 1536, X1, out);
}

// Round 17
// 1035.198 us; speedup vs baseline: 1.0241x; 1.0241x over previous
//
#include <hip/hip_runtime.h>
#include <hip/hip_bf16.h>
#include <stdint.h>

typedef uint16_t u16;
typedef uint32_t u32;
typedef float    f32x4  __attribute__((ext_vector_type(4)));
typedef __bf16   bf16x8 __attribute__((ext_vector_type(8)));
typedef u16      u16x8  __attribute__((ext_vector_type(8)));
typedef u16      u16x4  __attribute__((ext_vector_type(4)));
typedef u32      u32x2  __attribute__((ext_vector_type(2)));
typedef float    f32x4v __attribute__((ext_vector_type(4)));

// L=3120, D=1536, H=12, hd=128, FS=1560, NF=2, CACHE=6240, CTX=512, FF=8960
// current_start=3120 -> start_frame=2, window = [0,6240)

__device__ __forceinline__ u16 f2bf(float f) {
    u32 u = __builtin_bit_cast(u32, f);
    u32 r = u + 0x7fffu + ((u >> 16) & 1u);
    return (u16)(r >> 16);
}
__device__ __forceinline__ float bfbits2f(u32 ubits) {
    return __builtin_bit_cast(float, ubits << 16);
}
__device__ __forceinline__ u32 cvtpk(float a, float b) {
    u32 r;
    asm("v_cvt_pk_bf16_f32 %0, %1, %2" : "=v"(r) : "v"(a), "v"(b));
    return r;
}
__device__ __forceinline__ bf16x8 loadb8(const u16* p) {
    u16x8 u = *(const u16x8*)p;
    return __builtin_bit_cast(bf16x8, u);
}
__device__ __forceinline__ f32x4 mfma16(bf16x8 a, bf16x8 b, f32x4 c) {
    return __builtin_amdgcn_mfma_f32_16x16x32_bf16(a, b, c, 0, 0, 0);
}
__device__ __forceinline__ void gload16(const u16* gp, u16* lp) {
    __builtin_amdgcn_global_load_lds((const __attribute__((address_space(1))) void*)gp,
                                     (__attribute__((address_space(3))) void*)lp, 16, 0, 0);
}
__device__ __forceinline__ float blockSum(float v, volatile float* buf, int t) {
#pragma unroll
    for (int o = 1; o < 64; o <<= 1) v += __shfl_xor(v, o);
    if ((t & 63) == 0) buf[t >> 6] = v;
    __syncthreads();
    float r = buf[0] + buf[1] + buf[2] + buf[3];
    __syncthreads();
    return r;
}

// ---------- weight conversion ----------
struct ConvJob { const float* s; u16* d; int n4; };
struct ConvJobs { ConvJob j[12]; int cnt; };

__global__ void k_conv(ConvJobs js) {
    int tid = blockIdx.x * blockDim.x + threadIdx.x;
    int stride = gridDim.x * blockDim.x;
    for (int q = 0; q < js.cnt; q++) {
        const f32x4v* s = (const f32x4v*)js.j[q].s;
        u16x4* d = (u16x4*)js.j[q].d;
        int n4 = js.j[q].n4;
        for (int i = tid; i < n4; i += stride) {
            f32x4v v = s[i];
            u16x4 o;
            o[0] = f2bf(v[0]); o[1] = f2bf(v[1]); o[2] = f2bf(v[2]); o[3] = f2bf(v[3]);
            d[i] = o;
        }
    }
}

__global__ void k_mod(const float* __restrict__ sst, const float* __restrict__ temb, float* __restrict__ e) {
    int i = blockIdx.x * 256 + threadIdx.x;
    if (i < 18432) e[i] = sst[i % 9216] + temb[i];
}

// KV cache rows [0,3120): K -> row-major (12,6240,128); V -> transposed (12,128,6240)
__global__ void k_cachecvt(const float* __restrict__ kc, const float* __restrict__ vc,
                           u16* __restrict__ Ka, u16* __restrict__ Va) {
    int b = blockIdx.x;                       // 6 * 195
    int hd = (b % 6) * 256 + threadIdx.x;
    int p0 = (b / 6) * 16;
    int h = hd >> 7, d = hd & 127;
    u16x8 lo, hi;
#pragma unroll
    for (int j = 0; j < 16; j++) {
        long src = (long)(p0 + j) * 1536 + hd;
        Ka[(long)h * 798720 + (long)(p0 + j) * 128 + d] = f2bf(kc[src]);
        u16 v = f2bf(vc[src]);
        if (j < 8) lo[j] = v; else hi[j - 8] = v;
    }
    u16* dst = &Va[(long)h * 798720 + (long)d * 6240 + p0];
    *(u16x8*)dst = lo;
    *(u16x8*)(dst + 8) = hi;
}

// ---------- LayerNorm (+ optional per-frame modulation) ----------
__global__ __launch_bounds__(256) void k_ln(const float* __restrict__ x, u16* __restrict__ out,
                                            const float* __restrict__ mulp, const float* __restrict__ addp,
                                            int perFrame, int plusOne) {
    __shared__ float buf[4];
    const int row = blockIdx.x, t = threadIdx.x;
    const float* xr = x + (long)row * 1536;
    float v[6];
    float s = 0.f;
#pragma unroll
    for (int k = 0; k < 6; k++) { v[k] = xr[t + k * 256]; s += v[k]; }
    s = blockSum(s, buf, t);
    float mu = s * (1.f / 1536.f);
    float q = 0.f;
#pragma unroll
    for (int k = 0; k < 6; k++) { float d = v[k] - mu; q += d * d; }
    q = blockSum(q, buf, t);
    float inv = rsqrtf(q * (1.f / 1536.f) + 1e-6f);
    const int fo = perFrame ? (row / 1560) * 9216 : 0;
    u16* orow = out + (long)row * 1536;
    float add1 = plusOne ? 1.f : 0.f;
#pragma unroll
    for (int k = 0; k < 6; k++) {
        int c = t + k * 256;
        float m = mulp[fo + c] + add1;
        float y = (v[k] - mu) * inv * m + addp[fo + c];
        orow[c] = f2bf(y);
    }
}

// ---------- RMS over D=1536 on bf16 input (+bias, + optional RoPE), head-split out ----------
__global__ __launch_bounds__(256) void k_rmsrope(const u16* __restrict__ in, int ld, int colOff,
                                                 const float* __restrict__ bias,
                                                 const float* __restrict__ w,
                                                 u16* __restrict__ out, long headStride,
                                                 const float* __restrict__ fr, const float* __restrict__ fi,
                                                 int doRope) {
    __shared__ float buf[4];
    const int row = blockIdx.x, t = threadIdx.x;
    const u32* xr = (const u32*)(in + (long)row * ld + colOff);
    const float2* b2 = (const float2*)bias;
    float px[3], py[3];
    float ss = 0.f;
#pragma unroll
    for (int i = 0; i < 3; i++) {
        u32 u = xr[t * 3 + i];
        float2 bb = b2[t * 3 + i];
        px[i] = bfbits2f(u & 0xffffu) + bb.x;
        py[i] = bfbits2f(u >> 16) + bb.y;
        ss += px[i] * px[i] + py[i] * py[i];
    }
    ss = blockSum(ss, buf, t);
    float inv = rsqrtf(ss * (1.f / 1536.f) + 1e-6f);
    int frame = 0, gh = 0, gw = 0;
    if (doRope) { frame = row / 1560; int rem = row - frame * 1560; gh = rem / 52; gw = rem - gh * 52; }
    const float2* w2 = (const float2*)w;
#pragma unroll
    for (int i = 0; i < 3; i++) {
        int jg = t * 3 + i;
        int hh = jg >> 6, j = jg & 63;
        float2 ww = w2[jg];
        float a = px[i] * inv * ww.x, b = py[i] * inv * ww.y;
        float oa = a, ob = b;
        if (doRope) {
            int fidx = (j < 22) ? (2 + frame) : ((j < 43) ? gh : gw);
            float cs = fr[fidx * 64 + j], sn = fi[fidx * 64 + j];
            oa = a * cs - b * sn;
            ob = a * sn + b * cs;
        }
        u16* dst = out + (long)hh * headStride + (long)row * 128 + j * 2;
        dst[0] = f2bf(oa);
        dst[1] = f2bf(ob);
    }
}

// ---------- fused dual RMS+RoPE for self-path Q (cols 0..1535) and K (cols 1536..3071) of lin ----------
__global__ __launch_bounds__(256) void k_rmsrope2(const u16* __restrict__ in,  // lin, ld 4608
                                                  const float* __restrict__ bq, const float* __restrict__ wq,
                                                  const float* __restrict__ bk, const float* __restrict__ wk,
                                                  u16* __restrict__ outQ, u16* __restrict__ outK,
                                                  const float* __restrict__ fr, const float* __restrict__ fi) {
    __shared__ float buf[8];
    const int row = blockIdx.x, t = threadIdx.x;
    const u32* xq = (const u32*)(in + (long)row * 4608);
    const u32* xk = xq + 768;
    const float2* bq2 = (const float2*)bq;
    const float2* bk2 = (const float2*)bk;
    float qx[3], qy[3], kx[3], ky[3];
    float sq = 0.f, sk = 0.f;
#pragma unroll
    for (int i = 0; i < 3; i++) {
        u32 uq = xq[t * 3 + i];
        float2 bb = bq2[t * 3 + i];
        qx[i] = bfbits2f(uq & 0xffffu) + bb.x;
        qy[i] = bfbits2f(uq >> 16) + bb.y;
        sq += qx[i] * qx[i] + qy[i] * qy[i];
        u32 uk = xk[t * 3 + i];
        float2 bc = bk2[t * 3 + i];
        kx[i] = bfbits2f(uk & 0xffffu) + bc.x;
        ky[i] = bfbits2f(uk >> 16) + bc.y;
        sk += kx[i] * kx[i] + ky[i] * ky[i];
    }
    sq = blockSum(sq, buf, t);
    sk = blockSum(sk, buf + 4, t);
    float invq = rsqrtf(sq * (1.f / 1536.f) + 1e-6f);
    float invk = rsqrtf(sk * (1.f / 1536.f) + 1e-6f);
    int frame = row / 1560;
    int rem = row - frame * 1560;
    int gh = rem / 52, gw = rem - gh * 52;
    const float2* wq2 = (const float2*)wq;
    const float2* wk2 = (const float2*)wk;
#pragma unroll
    for (int i = 0; i < 3; i++) {
        int jg = t * 3 + i;
        int hh = jg >> 6, j = jg & 63;
        int fidx = (j < 22) ? (2 + frame) : ((j < 43) ? gh : gw);
        float cs = fr[fidx * 64 + j], sn = fi[fidx * 64 + j];
        float2 wwq = wq2[jg];
        float a = qx[i] * invq * wwq.x, b = qy[i] * invq * wwq.y;
        u16* dq = outQ + (long)hh * (3120L * 128) + (long)row * 128 + j * 2;
        dq[0] = f2bf(a * cs - b * sn);
        dq[1] = f2bf(a * sn + b * cs);
        float2 wwk = wk2[jg];
        float c2 = kx[i] * invk * wwk.x, d2 = ky[i] * invk * wwk.y;
        u16* dk = outK + (long)hh * (6240L * 128) + (long)row * 128 + j * 2;
        dk[0] = f2bf(c2 * cs - d2 * sn);
        dk[1] = f2bf(c2 * sn + d2 * cs);
    }
}

// ---------- scatter bf16 cols (+bias) into V-transposed head-split layout (16-wide) ----------
__global__ void k_scatterT(const u16* __restrict__ in, int ld, int colOff,
                           const float* __restrict__ bias, u16* __restrict__ outT,
                           int vstride, int posOff) {
    int hd = blockIdx.x * 256 + threadIdx.x;   // 0..1535
    int r0 = blockIdx.y * 16;
    int h = hd >> 7, d = hd & 127;
    float bi = bias[hd];
    u16x8 lo, hi;
#pragma unroll
    for (int j = 0; j < 16; j++) {
        u16 v = f2bf(bfbits2f(in[(long)(r0 + j) * ld + colOff + hd]) + bi);
        if (j < 8) lo[j] = v; else hi[j - 8] = v;
    }
    u16* dst = &outT[(long)h * 128 * vstride + (long)d * vstride + posOff + r0];
    *(u16x8*)dst = lo;
    *(u16x8*)(dst + 8) = hi;
}

// ---------- GEMM: C(MxN) = A(MxK) @ B(NxK)^T (+bias), tile BM x 128 ----------
// EPI 0: f32  1: bf16  2: bf16 gelu  3: f32 resid + v*gate  5: f32 split-K partial
struct GemmP {
    const u16* A; const u16* B; void* C;
    const float* bias; const float* gate; const float* resid;
    int M, N, K, ldA, ldB, ldC, kChunk;
};

template <int EPI, int BM>
__global__ __launch_bounds__(256) void k_gemm(GemmP g) {
    constexpr int WM = BM / 2;    // rows per m-wave
    constexpr int TM = BM / 32;   // m-frags per wave
    __shared__ alignas(16) u16 As[BM * 32];
    __shared__ alignas(16) u16 Bs[128 * 32];
    const int t = threadIdx.x;
    const int w = t >> 6, l = t & 63, lr = l & 15, lg = l >> 4;
    const int wm = w >> 1, wn = w & 1;
    const long m0 = (long)blockIdx.y * BM, n0 = (long)blockIdx.x * 128;
    f32x4 acc[TM][4];
#pragma unroll
    for (int a = 0; a < TM; a++)
#pragma unroll
        for (int b = 0; b < 4; b++) acc[a][b] = f32x4{0.f, 0.f, 0.f, 0.f};

    const int rowU = t >> 2, c8 = t & 3;
    long arow[2], brow[2];
#pragma unroll
    for (int i = 0; i < 2; i++) {
        long r = m0 + rowU + i * 64;
        if (r > (long)g.M - 1) r = g.M - 1;
        arow[i] = r;
        brow[i] = n0 + rowU + i * 64;
    }

    const int kBeg = blockIdx.z * g.kChunk;
    const int kEnd = min(g.K, kBeg + g.kChunk);
    for (int k0 = kBeg; k0 < kEnd; k0 += 32) {
        __syncthreads();
#pragma unroll
        for (int i = 0; i < BM / 64; i++)
            gload16(g.A + arow[i] * (long)g.ldA + k0 + c8 * 8, &As[(i * 256 + w * 64) * 8]);
#pragma unroll
        for (int i = 0; i < 2; i++)
            gload16(g.B + brow[i] * (long)g.ldB + k0 + c8 * 8, &Bs[(i * 256 + w * 64) * 8]);
        __syncthreads();
        bf16x8 am[TM], bn[4];
#pragma unroll
        for (int mi = 0; mi < TM; mi++) am[mi] = loadb8(&As[(wm * WM + mi * 16 + lr) * 32 + lg * 8]);
#pragma unroll
        for (int ni = 0; ni < 4; ni++) bn[ni] = loadb8(&Bs[(wn * 64 + ni * 16 + lr) * 32 + lg * 8]);
#pragma unroll
        for (int mi = 0; mi < TM; mi++)
#pragma unroll
            for (int ni = 0; ni < 4; ni++)
                acc[mi][ni] = mfma16(am[mi], bn[ni], acc[mi][ni]);
    }

#pragma unroll
    for (int mi = 0; mi < TM; mi++) {
#pragma unroll
        for (int ni = 0; ni < 4; ni++) {
            long col = n0 + wn * 64 + ni * 16 + lr;
            float bi = g.bias ? g.bias[col] : 0.f;
#pragma unroll
            for (int r = 0; r < 4; r++) {
                long row = m0 + wm * WM + mi * 16 + lg * 4 + r;
                if (row >= g.M) continue;
                float v = acc[mi][ni][r] + bi;
                if constexpr (EPI == 0) {
                    ((float*)g.C)[row * g.ldC + col] = v;
                } else if constexpr (EPI == 1) {
                    ((u16*)g.C)[row * g.ldC + col] = f2bf(v);
                } else if constexpr (EPI == 2) {
                    float x3 = v * v * v;
                    float gl = 0.5f * v * (1.f + tanhf(0.79788456080286536f * (v + 0.044715f * x3)));
                    ((u16*)g.C)[row * g.ldC + col] = f2bf(gl);
                } else if constexpr (EPI == 3) {
                    float gt = g.gate ? g.gate[(row / 1560) * 9216 + col] : 1.f;
                    ((float*)g.C)[row * g.ldC + col] = g.resid[row * g.ldC + col] + v * gt;
                } else { // 5: split-K partial
                    ((float*)g.C)[(long)blockIdx.z * ((long)g.M * g.ldC) + row * g.ldC + col] = v;
                }
            }
        }
    }
}

// ---------- 256x256 multi-phase GEMM (BK=64, dbuf LDS, XOR-swizzle, per-phase interleave) ----------
// EPI 1: bf16  2: bf16 gelu.
template <int EPI>
__global__ __launch_bounds__(512, 2) void k_gemm256(GemmP g) {
    __shared__ alignas(16) u16 As[2][16384];
    __shared__ alignas(16) u16 Bs[2][16384];
    const int t = threadIdx.x;
    const int wid = t >> 6, l = t & 63, lr = l & 15, lg = l >> 4;
    const int wm = wid >> 2, wn = wid & 3;
    const long m0 = (long)blockIdx.y * 256, n0 = (long)blockIdx.x * 256;
    const int nt = g.K >> 6;

    f32x4 acc[8][4];
#pragma unroll
    for (int a = 0; a < 8; a++)
#pragma unroll
        for (int b = 0; b < 4; b++) acc[a][b] = f32x4{0.f, 0.f, 0.f, 0.f};

    const int su = t >> 3;          // row-within-issue 0..63
    const int sc = t & 7;           // 16B chunk 0..7
    const int ldsBase = (wid << 9); // wave-uniform, u16 units

    auto stA = [&](int b, int tk, int j) {
        int r = j * 64 + su;
        long row = m0 + r; if (row > (long)g.M - 1) row = g.M - 1;
        gload16(g.A + row * (long)g.ldA + tk * 64 + ((sc ^ (r & 7)) * 8),
                &As[b][(j << 12) + ldsBase]);
    };
    auto stB = [&](int b, int tk, int j) {
        int r = j * 64 + su;
        long row = n0 + r; if (row > (long)g.N - 1) row = g.N - 1;
        gload16(g.B + row * (long)g.ldB + tk * 64 + ((sc ^ (r & 7)) * 8),
                &Bs[b][(j << 12) + ldsBase]);
    };

    // prologue: full tile 0 into buffer 0
#pragma unroll
    for (int j = 0; j < 4; j++) stA(0, 0, j);
#pragma unroll
    for (int j = 0; j < 4; j++) stB(0, 0, j);
    __syncthreads();

    for (int tk = 0; tk < nt; ++tk) {
        const int cur = tk & 1, nxt = cur ^ 1;
        const bool pre = (tk + 1 < nt);
        bf16x8 bB[4][2];
#pragma unroll
        for (int ph = 0; ph < 4; ++ph) {
            if (pre) {
                if (ph == 0) { stA(nxt, tk + 1, 0); stA(nxt, tk + 1, 1); stA(nxt, tk + 1, 2); stA(nxt, tk + 1, 3); }
                else if (ph == 1) { stB(nxt, tk + 1, 0); stB(nxt, tk + 1, 1); stB(nxt, tk + 1, 2); stB(nxt, tk + 1, 3); }
            }
            if (ph == 0) {
#pragma unroll
                for (int ni = 0; ni < 4; ni++)
#pragma unroll
                    for (int kk = 0; kk < 2; kk++) {
                        int row = wn * 64 + ni * 16 + lr;
                        bB[ni][kk] = loadb8(&Bs[cur][row * 64 + (((kk * 4 + lg) ^ (lr & 7)) * 8)]);
                    }
            }
            bf16x8 aA[2][2];
#pragma unroll
            for (int mi2 = 0; mi2 < 2; mi2++)
#pragma unroll
                for (int kk = 0; kk < 2; kk++) {
                    int row = wm * 128 + (ph * 2 + mi2) * 16 + lr;
                    aA[mi2][kk] = loadb8(&As[cur][row * 64 + (((kk * 4 + lg) ^ (lr & 7)) * 8)]);
                }
            __builtin_amdgcn_s_setprio(1);
#pragma unroll
            for (int mi2 = 0; mi2 < 2; mi2++)
#pragma unroll
                for (int ni = 0; ni < 4; ni++)
#pragma unroll
                    for (int kk = 0; kk < 2; kk++)
                        acc[ph * 2 + mi2][ni] = mfma16(aA[mi2][kk], bB[ni][kk], acc[ph * 2 + mi2][ni]);
            __builtin_amdgcn_s_setprio(0);
            __builtin_amdgcn_sched_barrier(0);
        }
        __syncthreads();
    }

#pragma unroll
    for (int mi = 0; mi < 8; mi++) {
#pragma unroll
        for (int ni = 0; ni < 4; ni++) {
            long col = n0 + wn * 64 + ni * 16 + lr;
            float bi = g.bias ? g.bias[col] : 0.f;
#pragma unroll
            for (int r = 0; r < 4; r++) {
                long row = m0 + wm * 128 + mi * 16 + lg * 4 + r;
                if (row >= g.M) continue;
                float v = acc[mi][ni][r] + bi;
                if constexpr (EPI == 1) {
                    ((u16*)g.C)[row * g.ldC + col] = f2bf(v);
                } else { // 2: gelu(tanh)
                    float x3 = v * v * v;
                    float gl = 0.5f * v * (1.f + tanhf(0.79788456080286536f * (v + 0.044715f * x3)));
                    ((u16*)g.C)[row * g.ldC + col] = f2bf(gl);
                }
            }
        }
    }
}

// ---------- split-K combine for FFN2: out = resid + (sum partials + bias)*gate ----------
__global__ void k_gcomb(const float* __restrict__ P, int S, long MN4,
                        const float* __restrict__ bias, const float* __restrict__ gate,
                        const float* __restrict__ resid, float* __restrict__ out) {
    long i = (long)blockIdx.x * 256 + threadIdx.x;
    if (i >= MN4) return;
    f32x4v a = ((const f32x4v*)P)[i];
    for (int s = 1; s < S; s++) {
        f32x4v b = ((const f32x4v*)P)[(long)s * MN4 + i];
        a[0] += b[0]; a[1] += b[1]; a[2] += b[2]; a[3] += b[3];
    }
    long e0 = i * 4;
    int col = (int)(e0 % 1536);
    int fo = (int)((e0 / 1536) / 1560) * 9216;
    f32x4v r = ((const f32x4v*)resid)[i];
#pragma unroll
    for (int j = 0; j < 4; j++)
        r[j] += (a[j] + bias[col + j]) * gate[fo + col + j];
    ((f32x4v*)out)[i] = r;
}

// ---------- split-K partial sum -> bf16 ----------
__global__ void k_sumbf(const float* __restrict__ P, int S, long N4, u16* __restrict__ out) {
    long i = (long)blockIdx.x * 256 + threadIdx.x;
    if (i >= N4) return;
    f32x4v a = ((const f32x4v*)P)[i];
#pragma unroll 3
    for (int s = 1; s < S; s++) {
        f32x4v b = ((const f32x4v*)P)[(long)s * N4 + i];
        a[0] += b[0]; a[1] += b[1]; a[2] += b[2]; a[3] += b[3];
    }
    u16x4 o;
    o[0] = f2bf(a[0]); o[1] = f2bf(a[1]); o[2] = f2bf(a[2]); o[3] = f2bf(a[3]);
    ((u16x4*)out)[i] = o;
}

// ---------- flash attention: swapped QK^T, in-register softmax, O^T accumulation ----------
__global__ __launch_bounds__(256) void k_flash(const u16* __restrict__ Qb, const u16* __restrict__ Kb,
                                               const u16* __restrict__ Vtg,
                                               u16* __restrict__ Opart, float2* __restrict__ ms,
                                               int kvLen, int qlen, int splitIters, int totIters) {
    __shared__ alignas(16) u16 Kt[32 * 136];   // [key][128+8]
    __shared__ alignas(16) u16 Vt[128 * 40];   // [d][32+8]
    __shared__ alignas(16) u16 Pt[4][32 * 40]; // per wave [q][32+8]
    const int t = threadIdx.x;
    const int w = t >> 6, l = t & 63, lr = l & 15, lg = l >> 4;
    const int head = blockIdx.y, z = blockIdx.z;
    const long q0 = (long)blockIdx.x * 128;
    const u16* Qh = Qb + (long)head * qlen * 128;
    const u16* Kh = Kb + (long)head * kvLen * 128;
    const u16* Vh = Vtg + (long)head * kvLen * 128; // [128][kvLen]
    constexpr float SCL2 = 0.08838834764831845f * 1.44269504088896f; // 1/sqrt(128) * log2(e)

    bf16x8 aq[2][4];
#pragma unroll
    for (int wq = 0; wq < 2; wq++)
#pragma unroll
        for (int c = 0; c < 4; c++) {
            long row = q0 + w * 32 + wq * 16 + lr;
            if (row > (long)qlen - 1) row = qlen - 1;
            aq[wq][c] = loadb8(Qh + row * 128 + c * 32 + lg * 8);
        }

    f32x4 o[2][8];
    float mrow[2] = {-1e30f, -1e30f}, srow[2] = {0.f, 0.f};  // srow per-lane partial until end
#pragma unroll
    for (int wq = 0; wq < 2; wq++)
#pragma unroll
        for (int db = 0; db < 8; db++) o[wq][db] = f32x4{0.f, 0.f, 0.f, 0.f};

    const int kr = t >> 4, c16 = (t & 15) * 8;
    const int vr = t >> 1, vh = (t & 1) * 16;

    const int it0 = z * splitIters;
    const int itN = min(totIters, it0 + splitIters);
    for (int kt = it0; kt < itN; kt++) {
        const long k0 = (long)kt * 32;
        __syncthreads();
        {
            u16x8 a0 = *(const u16x8*)(Kh + (k0 + kr) * 128 + c16);
            u16x8 a1 = *(const u16x8*)(Kh + (k0 + kr + 16) * 128 + c16);
            *(u16x8*)&Kt[kr * 136 + c16] = a0;
            *(u16x8*)&Kt[(kr + 16) * 136 + c16] = a1;
            u16x8 b0 = *(const u16x8*)(Vh + (long)vr * kvLen + k0 + vh);
            u16x8 b1 = *(const u16x8*)(Vh + (long)vr * kvLen + k0 + vh + 8);
            *(u16x8*)&Vt[vr * 40 + vh] = b0;
            *(u16x8*)&Vt[vr * 40 + vh + 8] = b1;
        }
        __syncthreads();

        f32x4 s[2][2];
#pragma unroll
        for (int kh = 0; kh < 2; kh++) {
            bf16x8 kf[4];
#pragma unroll
            for (int cb = 0; cb < 4; cb++)
                kf[cb] = loadb8(&Kt[(kh * 16 + lr) * 136 + cb * 32 + lg * 8]);
#pragma unroll
            for (int wq = 0; wq < 2; wq++) {
                f32x4 acc = f32x4{0.f, 0.f, 0.f, 0.f};
#pragma unroll
                for (int cb = 0; cb < 4; cb++) acc = mfma16(kf[cb], aq[wq][cb], acc);
                s[wq][kh] = acc;
            }
        }

#pragma unroll
        for (int wq = 0; wq < 2; wq++) {
            float pml = fmaxf(fmaxf(fmaxf(s[wq][0][0], s[wq][0][1]), fmaxf(s[wq][0][2], s[wq][0][3])),
                              fmaxf(fmaxf(s[wq][1][0], s[wq][1][1]), fmaxf(s[wq][1][2], s[wq][1][3])));
            if (__any(pml * SCL2 > mrow[wq] + 8.f)) {
                float pm = fmaxf(pml, __shfl_xor(pml, 16));
                pm = fmaxf(pm, __shfl_xor(pm, 32));
                float nm = fmaxf(mrow[wq], pm * SCL2);
                float fsc = exp2f(mrow[wq] - nm);
                mrow[wq] = nm;
                srow[wq] *= fsc;
#pragma unroll
                for (int db = 0; db < 8; db++) {
                    f32x4 t4 = o[wq][db];
                    t4[0] *= fsc; t4[1] *= fsc; t4[2] *= fsc; t4[3] *= fsc;
                    o[wq][db] = t4;
                }
            }
            float p[8];
#pragma unroll
            for (int kh = 0; kh < 2; kh++)
#pragma unroll
                for (int r = 0; r < 4; r++)
                    p[kh * 4 + r] = exp2f(fmaf(s[wq][kh][r], SCL2, -mrow[wq]));
            srow[wq] += ((p[0] + p[1]) + (p[2] + p[3])) + ((p[4] + p[5]) + (p[6] + p[7]));
            u32x2 wa, wb;
            wa[0] = cvtpk(p[0], p[1]); wa[1] = cvtpk(p[2], p[3]);
            wb[0] = cvtpk(p[4], p[5]); wb[1] = cvtpk(p[6], p[7]);
            u16* pp = &Pt[w][(wq * 16 + lr) * 40 + lg * 4];
            *(u32x2*)pp = wa;
            *(u32x2*)(pp + 16) = wb;
        }

        bf16x8 pb0 = loadb8(&Pt[w][lr * 40 + lg * 8]);
        bf16x8 pb1 = loadb8(&Pt[w][(16 + lr) * 40 + lg * 8]);
#pragma unroll
        for (int db = 0; db < 8; db++) {
            bf16x8 vf = loadb8(&Vt[(db * 16 + lr) * 40 + lg * 8]);
            o[0][db] = mfma16(vf, pb0, o[0][db]);
            o[1][db] = mfma16(vf, pb1, o[1][db]);
        }
    }

#pragma unroll
    for (int wq = 0; wq < 2; wq++) {
        srow[wq] += __shfl_xor(srow[wq], 16);
        srow[wq] += __shfl_xor(srow[wq], 32);
    }

    const long part = ((long)z * 12 + head) * qlen;
#pragma unroll
    for (int wq = 0; wq < 2; wq++) {
        long row = q0 + w * 32 + wq * 16 + lr;
        if (row < qlen) {
            if (lg == 0) {
                float2 v; v.x = mrow[wq]; v.y = srow[wq];
                ms[part + row] = v;
            }
#pragma unroll
            for (int db = 0; db < 8; db++) {
                u16x4 pk;
#pragma unroll
                for (int r = 0; r < 4; r++) pk[r] = f2bf(o[wq][db][r]);
                *(u16x4*)&Opart[(part + row) * 128 + db * 16 + lg * 4] = pk;
            }
        }
    }
}

// ---------- combine KV-split partials (m,l in log2 units) ----------
__global__ __launch_bounds__(256) void k_combine(const u16* __restrict__ Opart, const float2* __restrict__ ms,
                                                 u16* __restrict__ Ob, int qlen, int S) {
    int idx = blockIdx.x * 4 + (threadIdx.x >> 6);
    int l = threadIdx.x & 63;
    int h = idx / qlen, q = idx - h * qlen;
    float2 mm[6];
    float M = -1e30f;
    for (int s = 0; s < S; s++) {
        mm[s] = ms[((long)s * 12 + h) * qlen + q];
        M = fmaxf(M, mm[s].x);
    }
    float den = 0.f, a0 = 0.f, a1 = 0.f;
    for (int s = 0; s < S; s++) {
        float wgt = exp2f(mm[s].x - M);
        den += wgt * mm[s].y;
        u32 two = *(const u32*)&Opart[(((long)s * 12 + h) * qlen + q) * 128 + l * 2];
        a0 += wgt * bfbits2f(two & 0xffffu);
        a1 += wgt * bfbits2f(two >> 16);
    }
    float inv = 1.f / den;
    u32 o = ((u32)f2bf(a1 * inv) << 16) | (u32)f2bf(a0 * inv);
    *(u32*)&Ob[(long)q * 1536 + h * 128 + l * 2] = o;
}

// ---------- launch ----------
extern "C" void kernel_launch(void* const* d_in, const int* in_sizes, int n_in,
                              void* d_out, int out_size, void* d_ws, size_t ws_size,
                              hipStream_t stream) {
    const float* hs    = (const float*)d_in[0];
    const float* ctx   = (const float*)d_in[1];
    const float* temb  = (const float*)d_in[2];
    const float* fr    = (const float*)d_in[3];
    const float* fi    = (const float*)d_in[4];
    const float* kcache= (const float*)d_in[5];
    const float* vcache= (const float*)d_in[6];
    const float* sst   = (const float*)d_in[7];
    const float* Wq = (const float*)d_in[8],  *bq = (const float*)d_in[9];
    const float* Wk = (const float*)d_in[10], *bk = (const float*)d_in[11];
    const float* Wv = (const float*)d_in[12], *bv = (const float*)d_in[13];
    const float* Wo = (const float*)d_in[14], *bo = (const float*)d_in[15];
    const float* nqw = (const float*)d_in[16], *nkw = (const float*)d_in[17];
    const float* salnw = (const float*)d_in[18], *salnb = (const float*)d_in[19];
    const float* cWq = (const float*)d_in[20], *cbq = (const float*)d_in[21];
    const float* cWk = (const float*)d_in[22], *cbk = (const float*)d_in[23];
    const float* cWv = (const float*)d_in[24], *cbv = (const float*)d_in[25];
    const float* cWo = (const float*)d_in[26], *cbo = (const float*)d_in[27];
    const float* cnqw = (const float*)d_in[28], *cnkw = (const float*)d_in[29];
    const float* W1 = (const float*)d_in[30], *b1 = (const float*)d_in[31];
    const float* W2 = (const float*)d_in[32], *b2 = (const float*)d_in[33];
    float* out = (float*)d_out;

    char* base = (char*)d_ws;
    size_t off = 0;
    auto alloc = [&](size_t bytes) -> char* {
        char* p = base + off;
        off = (off + bytes + 255) & ~(size_t)255;
        return p;
    };
    float* e   = (float*)alloc(18432 * 4);
    u16* nbuf  = (u16*)alloc((size_t)3120 * 1536 * 2);
    u16* lin   = (u16*)alloc((size_t)3120 * 4608 * 2);   // qkv proj; also ms; also FFN2 partials (w/ Qb)
    u16* Qb    = (u16*)alloc((size_t)12 * 3120 * 128 * 2);
    u16* Ka    = (u16*)alloc((size_t)12 * 6240 * 128 * 2);
    u16* Va    = (u16*)alloc((size_t)12 * 6240 * 128 * 2); // TRANSPOSED (12,128,6240)
    u16* attnb = (u16*)alloc((size_t)3120 * 1536 * 2);
    float* X1  = (float*)alloc((size_t)3120 * 1536 * 4);
    u16* CKb   = (u16*)alloc((size_t)12 * 512 * 128 * 2);
    u16* CVt   = (u16*)alloc((size_t)12 * 512 * 128 * 2);  // TRANSPOSED (12,128,512)
    u16* H1    = (u16*)alloc((size_t)3120 * 8960 * 2);   // FFN hidden; also Opart; also cKV partials
    u16* wqkv_b= (u16*)alloc((size_t)4608 * 1536 * 2);
    u16* wo_b  = (u16*)alloc((size_t)1536 * 1536 * 2);
    u16* cwq_b = (u16*)alloc((size_t)1536 * 1536 * 2);
    u16* cwkv_b= (u16*)alloc((size_t)3072 * 1536 * 2);
    u16* cwo_b = (u16*)alloc((size_t)1536 * 1536 * 2);
    u16* w1_b  = (u16*)alloc((size_t)8960 * 1536 * 2);
    u16* w2_b  = (u16*)alloc((size_t)8960 * 1536 * 2);
    u16* ctxb  = (u16*)alloc((size_t)512 * 1536 * 2);

    u16* Opart = H1;              // 5*12*3120*128 bf16 = 47.9MB < 55.9MB
    float2* msb = (float2*)lin;   // 5*12*3120 float2
    float* pbuf = (float*)lin;    // FFN2 partials: 2*3120*1536*4 = 38.3MB = lin+Qb, both dead
    float* cpart = (float*)H1;    // cKV partials: 4*512*3072*4 = 25.2MB

    // 1. convert weights + ctx to bf16
    ConvJobs cj{};
    auto setj = [&](int i, const float* s, u16* d, int n) { cj.j[i].s = s; cj.j[i].d = d; cj.j[i].n4 = n / 4; };
    setj(0, Wq, wqkv_b, 1536 * 1536);
    setj(1, Wk, wqkv_b + (size_t)1536 * 1536, 1536 * 1536);
    setj(2, Wv, wqkv_b + (size_t)2 * 1536 * 1536, 1536 * 1536);
    setj(3, Wo, wo_b, 1536 * 1536);
    setj(4, cWq, cwq_b, 1536 * 1536);
    setj(5, cWk, cwkv_b, 1536 * 1536);
    setj(6, cWv, cwkv_b + (size_t)1536 * 1536, 1536 * 1536);
    setj(7, cWo, cwo_b, 1536 * 1536);
    setj(8, W1, w1_b, 8960 * 1536);
    setj(9, W2, w2_b, 8960 * 1536);
    setj(10, ctx, ctxb, 512 * 1536);
    cj.cnt = 11;
    k_conv<<<2048, 256, 0, stream>>>(cj);

    // 2. modulation + cache repack (K row-major, V transposed)
    k_mod<<<72, 256, 0, stream>>>(sst, temb, e);
    k_cachecvt<<<1170, 256, 0, stream>>>(kcache, vcache, Ka, Va);

    // 3. nh = LN(x)*(1+scale)+shift
    k_ln<<<3120, 256, 0, stream>>>(hs, nbuf, e + 1536, e + 0, 1, 1);

    // 4. fused QKV projection (256² multi-phase) -> lin, then fused dual RMS/RoPE + scatterT
    GemmP gqkv{nbuf, wqkv_b, lin, nullptr, nullptr, nullptr, 3120, 4608, 1536, 1536, 1536, 4608, 1536};
    k_gemm256<1><<<dim3(18, 13), 512, 0, stream>>>(gqkv);
    k_rmsrope2<<<3120, 256, 0, stream>>>(lin, bq, nqw, bk, nkw, Qb, Ka + (size_t)3120 * 128, fr, fi);
    k_scatterT<<<dim3(6, 195), 256, 0, stream>>>(lin, 4608, 3072, bv, Va, 6240, 3120);

    // 5. self-attention: 195 tiles of 32 keys, split 5 (39 each)
    k_flash<<<dim3(25, 12, 5), 256, 0, stream>>>(Qb, Ka, Va, Opart, msb, 6240, 3120, 39, 195);
    k_combine<<<9360, 256, 0, stream>>>(Opart, msb, attnb, 3120, 5);

    // 6. x1 = x + (attn@Wo^T + bo)*gate
    GemmP gwo{attnb, wo_b, X1, bo, e + 2 * 1536, hs, 3120, 1536, 1536, 1536, 1536, 1536, 1536};
    k_gemm<3, 64><<<dim3(12, 49), 256, 0, stream>>>(gwo);

    // 7. n2 = LN(x1)*saln_w + saln_b
    k_ln<<<3120, 256, 0, stream>>>(X1, nbuf, salnw, salnb, 0, 0);

    // 8. cross-attn projections
    GemmP gcq{nbuf, cwq_b, lin, nullptr, nullptr, nullptr, 3120, 1536, 1536, 1536, 1536, 1536, 1536};
    k_gemm<1, 64><<<dim3(12, 49), 256, 0, stream>>>(gcq);
    k_rmsrope<<<3120, 256, 0, stream>>>(lin, 1536, 0, cbq, cnqw, Qb, (long)3120 * 128, fr, fi, 0);

    GemmP gckv{ctxb, cwkv_b, cpart, nullptr, nullptr, nullptr, 512, 3072, 1536, 1536, 1536, 3072, 384};
    k_gemm<5, 64><<<dim3(24, 8, 4), 256, 0, stream>>>(gckv);
    k_sumbf<<<1536, 256, 0, stream>>>(cpart, 4, 393216, lin);
    k_rmsrope<<<512, 256, 0, stream>>>(lin, 3072, 0, cbk, cnkw, CKb, (long)512 * 128, fr, fi, 0);
    k_scatterT<<<dim3(6, 32), 256, 0, stream>>>(lin, 3072, 1536, cbv, CVt, 512, 0);

    // 9. cross-attention: 16 tiles of 32 keys, split 2 (8 each)
    k_flash<<<dim3(25, 12, 2), 256, 0, stream>>>(Qb, CKb, CVt, Opart, msb, 512, 3120, 8, 16);
    k_combine<<<9360, 256, 0, stream>>>(Opart, msb, attnb, 3120, 2);

    // 10. x2 = x1 + ca@cWo^T + cbo   (in-place on X1)
    GemmP gcwo{attnb, cwo_b, X1, cbo, nullptr, X1, 3120, 1536, 1536, 1536, 1536, 1536, 1536};
    k_gemm<3, 64><<<dim3(12, 49), 256, 0, stream>>>(gcwo);

    // 11. n3 = LN(x2)*(1+c_scale)+c_shift
    k_ln<<<3120, 256, 0, stream>>>(X1, nbuf, e + 4 * 1536, e + 3 * 1536, 1, 1);

    // 12. FFN: FFN1 256² multi-phase; FFN2 BM=64 split-K x2 + combine
    GemmP g1{nbuf, w1_b, H1, b1, nullptr, nullptr, 3120, 8960, 1536, 1536, 1536, 8960, 1536};
    k_gemm256<2><<<dim3(35, 13), 512, 0, stream>>>(g1);

    GemmP g2{H1, w2_b, pbuf, nullptr, nullptr, nullptr, 3120, 1536, 8960, 8960, 8960, 1536, 4480};
    k_gemm<5, 64><<<dim3(12, 49, 2), 256, 0, stream>>>(g2);
    k_gcomb<<<4680, 256, 0, stream>>>(pbuf, 2, 1198080, b2, e + 5 * 1536, X1, out);
}